// Round 5
// baseline (213.035 us; speedup 1.0000x reference)
//
#include <hip/hip_runtime.h>
#include <hip/hip_bf16.h>
#include <math.h>

#define S 1024
#define D 1024
#define P 2816
#define R 64
#define E 8
#define M 16
#define DSPLIT 8
#define KSPLIT 4
#define KQ (P / KSPLIT)   // 704
#define NIT (KQ / 64)     // 11

typedef __attribute__((ext_vector_type(8))) short short8;   // 8 bf16 (4 VGPRs)
typedef __attribute__((ext_vector_type(4))) float floatx4;  // MFMA acc

static __device__ inline unsigned short f2bf(float f) {
  __hip_bfloat16 h = __float2bfloat16(f);
  return *reinterpret_cast<unsigned short*>(&h);
}

// ---------------------------------------------------------------------------
// K1 (fused): zero out+tbuf32, softmax/mix bases (bf16), counting sort (b0).
// grid 256 x 256.
// ---------------------------------------------------------------------------
__global__ __launch_bounds__(256) void k_pre(
    const float* __restrict__ up_logits, const float* __restrict__ gate_logits,
    const float* __restrict__ up_bank, const float* __restrict__ gate_bank,
    const int* __restrict__ idx,
    unsigned short* __restrict__ mxu, unsigned short* __restrict__ mxg,
    int* __restrict__ perm, int* __restrict__ offs, float* __restrict__ out,
    float* __restrict__ tbuf32) {
  int b = blockIdx.x, t = threadIdx.x;
  // zero the output slice (k_down accumulates with atomics)
  float4 z4 = make_float4(0.f, 0.f, 0.f, 0.f);
#pragma unroll
  for (int j = 0; j < 4; ++j)
    *(float4*)(out + (size_t)b * 4096 + j * 1024 + t * 4) = z4;
  // zero tbuf32 slice (k_t accumulates with atomics): 512 floats/block
  *(float2*)(tbuf32 + (size_t)b * 512 + t * 2) = make_float2(0.f, 0.f);

  if (b == 0) {  // counting sort, 4 tokens/thread
    __shared__ int hist[E];
    __shared__ int basearr[E];
    if (t < E) hist[t] = 0;
    __syncthreads();
    int e4[4];
#pragma unroll
    for (int j = 0; j < 4; ++j) {
      e4[j] = idx[t + j * 256];
      atomicAdd(&hist[e4[j]], 1);
    }
    __syncthreads();
    if (t == 0) {
      int run = 0;
      for (int i = 0; i < E; ++i) { basearr[i] = run; offs[i] = run; run += hist[i]; }
      offs[E] = S;
    }
    __syncthreads();
#pragma unroll
    for (int j = 0; j < 4; ++j) {
      int pos = atomicAdd(&basearr[e4[j]], 1);
      perm[pos] = t + j * 256;
    }
  }

  __shared__ float alpha[2][E][M];
  if (t < 16) {
    int mat = t >> 3, e = t & 7;
    const float* lg = (mat ? gate_logits : up_logits) + e * M;
    float v[M], mx = -1e30f, s = 0.f;
#pragma unroll
    for (int m = 0; m < M; ++m) { v[m] = lg[m]; mx = fmaxf(mx, v[m]); }
#pragma unroll
    for (int m = 0; m < M; ++m) { v[m] = expf(v[m] - mx); s += v[m]; }
#pragma unroll
    for (int m = 0; m < M; ++m) alpha[mat][e][m] = v[m] / s;
  }
  __syncthreads();
  int g = b * 256 + t;
  int d = g >> 6, r = g & 63;
  float au[E] = {0, 0, 0, 0, 0, 0, 0, 0}, ag[E] = {0, 0, 0, 0, 0, 0, 0, 0};
#pragma unroll
  for (int m = 0; m < M; ++m) {
    float vu = up_bank[((size_t)m * D + d) * R + r];
    float vg = gate_bank[((size_t)m * D + d) * R + r];
#pragma unroll
    for (int e = 0; e < E; ++e) {
      au[e] += alpha[0][e][m] * vu;
      ag[e] += alpha[1][e][m] * vg;
    }
  }
#pragma unroll
  for (int e = 0; e < E; ++e) {
    mxu[((size_t)e * D + d) * R + r] = f2bf(au[e]);
    mxg[((size_t)e * D + d) * R + r] = f2bf(ag[e]);
  }
}

// ---------------------------------------------------------------------------
// K2 (MFMA): t-partials, atomically accumulated into tbuf32 (fp32).
// grid (E, 4 tok-tiles of 64, DSPLIT=8), block 256. Wave: 16 tok x 128 n.
// ---------------------------------------------------------------------------
__global__ __launch_bounds__(256) void k_t(
    const float* __restrict__ H, const unsigned short* __restrict__ mxu,
    const unsigned short* __restrict__ mxg, const int* __restrict__ perm,
    const int* __restrict__ offs, float* __restrict__ tbuf32) {
  int e = blockIdx.x;
  int start = offs[e] + blockIdx.y * 64;
  int end = offs[e + 1];
  if (start >= end) return;
  int z = blockIdx.z;  // k-range [z*128, z*128+128)
  __shared__ unsigned short As[64][72];
  __shared__ unsigned short Bs[128][72];
  int t = threadIdx.x;
  int lane = t & 63, w = t >> 6, quad = lane >> 4, l15 = lane & 15;
  int rows[2];
#pragma unroll
  for (int j = 0; j < 2; ++j) {
    int c = t + j * 256;
    int pos = start + (c >> 3);
    rows[j] = (pos < end) ? perm[pos] : -1;
  }
  floatx4 acc[8];
#pragma unroll
  for (int nt = 0; nt < 8; ++nt) acc[nt] = (floatx4){0.f, 0.f, 0.f, 0.f};

  for (int it = 0; it < 2; ++it) {
    int k0 = z * 128 + it * 64;
    // A-stage: 64x64, fp32 H gather -> bf16
#pragma unroll
    for (int j = 0; j < 2; ++j) {
      int c = t + j * 256;
      int arow = c >> 3, acol = (c & 7) * 8;
      short8 v = (short8){0, 0, 0, 0, 0, 0, 0, 0};
      if (rows[j] >= 0) {
        const float* src = H + (size_t)rows[j] * D + k0 + acol;
        float4 f0 = *(const float4*)src;
        float4 f1 = *(const float4*)(src + 4);
        v[0] = f2bf(f0.x); v[1] = f2bf(f0.y); v[2] = f2bf(f0.z); v[3] = f2bf(f0.w);
        v[4] = f2bf(f1.x); v[5] = f2bf(f1.y); v[6] = f2bf(f1.z); v[7] = f2bf(f1.w);
      }
      *(short8*)&As[arow][acol] = v;
    }
    // B-stage transpose: mixed[e][k][r] -> Bs[n=r (u) | 64+r (g)][k_local]
    {
      int dd = t >> 2, r0 = (t & 3) * 16;
      const unsigned short* su = mxu + ((size_t)e * D + k0 + dd) * R + r0;
      const unsigned short* sg = mxg + ((size_t)e * D + k0 + dd) * R + r0;
      short8 u0 = *(const short8*)su, u1 = *(const short8*)(su + 8);
      short8 g0 = *(const short8*)sg, g1 = *(const short8*)(sg + 8);
#pragma unroll
      for (int j = 0; j < 8; ++j) {
        Bs[r0 + j][dd] = u0[j];
        Bs[r0 + 8 + j][dd] = u1[j];
        Bs[64 + r0 + j][dd] = g0[j];
        Bs[64 + r0 + 8 + j][dd] = g1[j];
      }
    }
    __syncthreads();
#pragma unroll
    for (int ks = 0; ks < 2; ++ks) {
      int kc = ks * 32 + quad * 8;
      short8 a = *(const short8*)&As[w * 16 + l15][kc];
#pragma unroll
      for (int nt = 0; nt < 8; ++nt) {
        short8 bb = *(const short8*)&Bs[nt * 16 + l15][kc];
        acc[nt] = __builtin_amdgcn_mfma_f32_16x16x32_bf16(a, bb, acc[nt], 0, 0, 0);
      }
    }
    __syncthreads();
  }
#pragma unroll
  for (int reg = 0; reg < 4; ++reg) {
    int pos = start + w * 16 + quad * 4 + reg;
    if (pos < end) {
#pragma unroll
      for (int nt = 0; nt < 8; ++nt)
        atomicAdd(&tbuf32[(size_t)pos * 128 + nt * 16 + l15], acc[nt][reg]);
    }
  }
}

// ---------------------------------------------------------------------------
// K3 (MFMA): inter[pos, p] = silu(t_g @ Ag[p]) * (t_u @ Au[p]), bf16 out.
// grid (E, 2 tiles of 128 tok, P/64=44), block 256 (4 waves, 32tok x 64p).
// Reads fp32 tbuf32 (conversion fused into staging). Single barrier,
// 32 MFMA per wave per launch.
// ---------------------------------------------------------------------------
__global__ __launch_bounds__(256) void k_inter(
    const float* __restrict__ tbuf32, const float* __restrict__ Aup,
    const float* __restrict__ Agate, const int* __restrict__ offs,
    unsigned short* __restrict__ inter) {
  int e = blockIdx.x;
  int start = offs[e] + blockIdx.y * 128;
  int end = offs[e + 1];
  if (start >= end) return;
  int p0 = blockIdx.z * 64;
  __shared__ unsigned short Ts[128][136];  // 128 tok x 128 r (u|g)
  __shared__ unsigned short Bu[64][72];    // 64 p x 64 r
  __shared__ unsigned short Bg[64][72];
  int t = threadIdx.x;
  int lane = t & 63, w = t >> 6, quad = lane >> 4, l15 = lane & 15;
  // stage T: 128 rows x 128 cols fp32 -> bf16; 8 chunks of 8 floats/thread
#pragma unroll
  for (int j = 0; j < 8; ++j) {
    int i = t + j * 256;
    int row = i >> 4, c8 = (i & 15) * 8;
    int pos = start + row;
    short8 v = (short8){0, 0, 0, 0, 0, 0, 0, 0};
    if (pos < end) {
      const float* src = tbuf32 + (size_t)pos * 128 + c8;
      float4 f0 = *(const float4*)src;
      float4 f1 = *(const float4*)(src + 4);
      v[0] = f2bf(f0.x); v[1] = f2bf(f0.y); v[2] = f2bf(f0.z); v[3] = f2bf(f0.w);
      v[4] = f2bf(f1.x); v[5] = f2bf(f1.y); v[6] = f2bf(f1.z); v[7] = f2bf(f1.w);
    }
    *(short8*)&Ts[row][c8] = v;
  }
  // stage Bu/Bg: 64p x 64r fp32 -> bf16; 2 chunks of 8 floats/thread each mat
#pragma unroll
  for (int j = 0; j < 2; ++j) {
    int i = t + j * 256;
    int pr = i >> 3, c8 = (i & 7) * 8;
    const float* su = Aup + ((size_t)(e * P + p0 + pr) * R + c8);
    const float* sg = Agate + ((size_t)(e * P + p0 + pr) * R + c8);
    float4 u0 = *(const float4*)su, u1 = *(const float4*)(su + 4);
    float4 g0 = *(const float4*)sg, g1 = *(const float4*)(sg + 4);
    short8 uv, gv;
    uv[0] = f2bf(u0.x); uv[1] = f2bf(u0.y); uv[2] = f2bf(u0.z); uv[3] = f2bf(u0.w);
    uv[4] = f2bf(u1.x); uv[5] = f2bf(u1.y); uv[6] = f2bf(u1.z); uv[7] = f2bf(u1.w);
    gv[0] = f2bf(g0.x); gv[1] = f2bf(g0.y); gv[2] = f2bf(g0.z); gv[3] = f2bf(g0.w);
    gv[4] = f2bf(g1.x); gv[5] = f2bf(g1.y); gv[6] = f2bf(g1.z); gv[7] = f2bf(g1.w);
    *(short8*)&Bu[pr][c8] = uv;
    *(short8*)&Bg[pr][c8] = gv;
  }
  __syncthreads();
  floatx4 au_acc[2][4], ag_acc[2][4];
#pragma unroll
  for (int tt = 0; tt < 2; ++tt)
#pragma unroll
    for (int pt = 0; pt < 4; ++pt) {
      au_acc[tt][pt] = (floatx4){0.f, 0.f, 0.f, 0.f};
      ag_acc[tt][pt] = (floatx4){0.f, 0.f, 0.f, 0.f};
    }
#pragma unroll
  for (int kh = 0; kh < 2; ++kh) {
    int kc = kh * 32 + quad * 8;
    short8 au[2], ag[2], bu[4], bg[4];
#pragma unroll
    for (int tt = 0; tt < 2; ++tt) {
      au[tt] = *(const short8*)&Ts[w * 32 + tt * 16 + l15][kc];
      ag[tt] = *(const short8*)&Ts[w * 32 + tt * 16 + l15][64 + kc];
    }
#pragma unroll
    for (int pt = 0; pt < 4; ++pt) {
      bu[pt] = *(const short8*)&Bu[pt * 16 + l15][kc];
      bg[pt] = *(const short8*)&Bg[pt * 16 + l15][kc];
    }
#pragma unroll
    for (int tt = 0; tt < 2; ++tt)
#pragma unroll
      for (int pt = 0; pt < 4; ++pt) {
        au_acc[tt][pt] = __builtin_amdgcn_mfma_f32_16x16x32_bf16(au[tt], bu[pt], au_acc[tt][pt], 0, 0, 0);
        ag_acc[tt][pt] = __builtin_amdgcn_mfma_f32_16x16x32_bf16(ag[tt], bg[pt], ag_acc[tt][pt], 0, 0, 0);
      }
  }
#pragma unroll
  for (int tt = 0; tt < 2; ++tt)
#pragma unroll
    for (int reg = 0; reg < 4; ++reg) {
      int row = w * 32 + tt * 16 + quad * 4 + reg;
      int pos = start + row;
      if (pos < end) {
#pragma unroll
        for (int pt = 0; pt < 4; ++pt) {
          float g = ag_acc[tt][pt][reg];
          float u = au_acc[tt][pt][reg];
          float val = u * (g / (1.f + __expf(-g)));
          inter[(size_t)pos * P + p0 + pt * 16 + l15] = f2bf(val);
        }
      }
    }
}

// ---------------------------------------------------------------------------
// K4 (MFMA): out[tok, d] += wts[tok] * (inter @ Wd^T), register-prefetched.
// grid (E, KSPLIT=4, D/64=16), block 256. Tile 256 tok x 64 d, BK=64.
// gridDim.x == E == 8 -> expert-e blocks land on XCD e (A re-reads L2-local).
// ---------------------------------------------------------------------------
__global__ __launch_bounds__(256) void k_down(
    const unsigned short* __restrict__ inter, const float* __restrict__ Wd,
    const int* __restrict__ perm, const int* __restrict__ offs,
    const float* __restrict__ wts, float* __restrict__ out) {
  int e = blockIdx.x;
  int start = offs[e];
  int end = offs[e + 1];
  if (start >= end) return;
  int kz = blockIdx.y;
  int d0 = blockIdx.z * 64;
  __shared__ unsigned short As[256][72];  // 36.9 KB
  __shared__ unsigned short Bs[64][72];   //  9.2 KB
  int t = threadIdx.x;
  int lane = t & 63, w = t >> 6, quad = lane >> 4, l15 = lane & 15;

  const unsigned short* aptr[8];
  bool aok[8];
#pragma unroll
  for (int j = 0; j < 8; ++j) {
    int arow = (t >> 3) + 32 * j;
    int pos = start + arow;
    aok[j] = (pos < end);
    aptr[j] = inter + (size_t)(aok[j] ? pos : start) * P + kz * KQ + (t & 7) * 8;
  }
  const float* bsrc = Wd + ((size_t)(e * D + d0 + (t >> 2)) * P + kz * KQ + (t & 3) * 16);

  float4 pa[8];
  float4 pb[4];
#pragma unroll
  for (int j = 0; j < 8; ++j)
    pa[j] = aok[j] ? *(const float4*)(aptr[j]) : make_float4(0.f, 0.f, 0.f, 0.f);
#pragma unroll
  for (int q = 0; q < 4; ++q) pb[q] = *(const float4*)(bsrc + q * 4);

  floatx4 acc[4][4];
#pragma unroll
  for (int tt = 0; tt < 4; ++tt)
#pragma unroll
    for (int dt = 0; dt < 4; ++dt) acc[tt][dt] = (floatx4){0.f, 0.f, 0.f, 0.f};

  for (int it = 0; it < NIT; ++it) {
#pragma unroll
    for (int j = 0; j < 8; ++j)
      *(float4*)&As[(t >> 3) + 32 * j][(t & 7) * 8] = pa[j];
    {
      short8 bv0, bv1;
      bv0[0] = f2bf(pb[0].x); bv0[1] = f2bf(pb[0].y); bv0[2] = f2bf(pb[0].z); bv0[3] = f2bf(pb[0].w);
      bv0[4] = f2bf(pb[1].x); bv0[5] = f2bf(pb[1].y); bv0[6] = f2bf(pb[1].z); bv0[7] = f2bf(pb[1].w);
      bv1[0] = f2bf(pb[2].x); bv1[1] = f2bf(pb[2].y); bv1[2] = f2bf(pb[2].z); bv1[3] = f2bf(pb[2].w);
      bv1[4] = f2bf(pb[3].x); bv1[5] = f2bf(pb[3].y); bv1[6] = f2bf(pb[3].z); bv1[7] = f2bf(pb[3].w);
      *(short8*)&Bs[t >> 2][(t & 3) * 16] = bv0;
      *(short8*)&Bs[t >> 2][(t & 3) * 16 + 8] = bv1;
    }
    __syncthreads();
    if (it + 1 < NIT) {
      int k0 = (it + 1) * 64;
#pragma unroll
      for (int j = 0; j < 8; ++j)
        pa[j] = aok[j] ? *(const float4*)(aptr[j] + k0) : make_float4(0.f, 0.f, 0.f, 0.f);
#pragma unroll
      for (int q = 0; q < 4; ++q) pb[q] = *(const float4*)(bsrc + k0 + q * 4);
    }
#pragma unroll
    for (int ks = 0; ks < 2; ++ks) {
      int kc = ks * 32 + quad * 8;
      short8 a[4], b[4];
#pragma unroll
      for (int tt = 0; tt < 4; ++tt) a[tt] = *(const short8*)&As[w * 64 + tt * 16 + l15][kc];
#pragma unroll
      for (int dt = 0; dt < 4; ++dt) b[dt] = *(const short8*)&Bs[dt * 16 + l15][kc];
#pragma unroll
      for (int tt = 0; tt < 4; ++tt)
#pragma unroll
        for (int dt = 0; dt < 4; ++dt)
          acc[tt][dt] = __builtin_amdgcn_mfma_f32_16x16x32_bf16(a[tt], b[dt], acc[tt][dt], 0, 0, 0);
    }
    __syncthreads();
  }
#pragma unroll
  for (int tt = 0; tt < 4; ++tt)
#pragma unroll
    for (int reg = 0; reg < 4; ++reg) {
      int pos = start + w * 64 + tt * 16 + quad * 4 + reg;
      if (pos < end) {
        int tok = perm[pos];
        float wt = wts[tok];
#pragma unroll
        for (int dt = 0; dt < 4; ++dt)
          atomicAdd(&out[(size_t)tok * D + d0 + dt * 16 + l15], acc[tt][dt][reg] * wt);
      }
    }
}

// ---------------------------------------------------------------------------
extern "C" void kernel_launch(void* const* d_in, const int* in_sizes, int n_in,
                              void* d_out, int out_size, void* d_ws, size_t ws_size,
                              hipStream_t stream) {
  const float* H = (const float*)d_in[0];
  const int* idx = (const int*)d_in[1];
  const float* wts = (const float*)d_in[2];
  const float* Aup = (const float*)d_in[3];
  const float* Agate = (const float*)d_in[4];
  const float* upl = (const float*)d_in[5];
  const float* gatel = (const float*)d_in[6];
  const float* Wd = (const float*)d_in[7];
  const float* upb = (const float*)d_in[8];
  const float* gateb = (const float*)d_in[9];
  float* out = (float*)d_out;

  char* ws = (char*)d_ws;
  unsigned short* mxu = (unsigned short*)ws;                 // E*D*R bf16 = 1 MB
  unsigned short* mxg = mxu + (size_t)E * D * R;             // 1 MB
  float* tbuf32 = (float*)(mxg + (size_t)E * D * R);         // S*128 f32 = 512 KB
  unsigned short* inter = (unsigned short*)(tbuf32 + (size_t)S * 128);  // S*P bf16
  int* perm = (int*)(inter + (size_t)S * P);
  int* offs = perm + S;

  k_pre<<<256, 256, 0, stream>>>(upl, gatel, upb, gateb, idx, mxu, mxg, perm, offs, out, tbuf32);
  k_t<<<dim3(E, 4, DSPLIT), 256, 0, stream>>>(H, mxu, mxg, perm, offs, tbuf32);
  k_inter<<<dim3(E, 2, P / 64), 256, 0, stream>>>(tbuf32, Aup, Agate, offs, inter);
  k_down<<<dim3(E, KSPLIT, D / 64), 256, 0, stream>>>(inter, Wd, perm, offs, wts, out);
}